// Round 13
// baseline (3998.819 us; speedup 1.0000x reference)
//
#include <hip/hip_runtime.h>
#include <hip/hip_bf16.h>
#include <cstddef>

// ---------------------------------------------------------------------------
// B=64, S=256, W=256, E=512, HID=1024, L=2, NCLS=10
// xsplit + WencT split -> enc MFMA GEMM -> ONE fused dual-layer LSTM:
//   512 blocks x 256 threads (4 waves), 2 blocks/CU (launch_bounds(256,2)).
//   bid<256 = layer0 block owning h-cols lb*4..+3 (K=1536, [Wh0;Wx0]);
//   bid>=256 = layer1 block (K=2048, [Wh1;Wx1]). Round-robin dispatch pairs
//   one L0 + one L1 block per CU -> layer spins overlap the other layer's
//   MFMA on the same SIMDs.
//   State: Y0/H1 write-once slot arrays (slot t+1 = h after step t), 8B
//   write-through agent atomics (4 cols/block -> 8B granule halves; consumer
//   16B reads span 2 producers, both flag-covered).
//   Sync: per-block flag[bid]=r, published by WAVE 0 ONLY after its own
//   granule stores + inline vmcnt(0) drain (no trailing block barrier; waves
//   1-3 run ahead). Consumers poll 64 producer flags with 64 lanes.
// -> classifier.
// Fragment layouts (HW-validated rounds 4/6..12, absmax <= 7.6e-6):
//   A/B operand: lane = (idx&15) + 16*kg holds 8 values [idx][k0+kg*8 .. +7]
//   D: row = (lane>>4)*4 + rr, col = nj*16 + (lane&15)   (single 16-row tile)
// Granule layouts:
//   W:  Wf[lb(256)][plane][s][lane][8]  (512 shorts per (lb,p,s))
//   h slot: [plane][s(32)][nj][lane][8] (plane stride 65536 sh, slot 131072)
//   E:  Ef[t][plane][s(16)][nj][lane][8] (plane stride 32768 sh)
// Row permutation: gate row j = g*1024 + lb*4 + c -> block lb, rloc = g*4+c.
// Workspace ~245 MB (known-good budget >= 279 MB).
// ---------------------------------------------------------------------------

using short8 = __attribute__((ext_vector_type(8))) short;
using f32x4  = __attribute__((ext_vector_type(4))) float;

#define LD8(p) (*reinterpret_cast<const short8*>(p))

__device__ __forceinline__ float sigmoidf_(float x) {
    return 1.f / (1.f + __expf(-x));
}
__device__ __forceinline__ unsigned short f2bf(float x) {   // RNE bf16
    union { float f; unsigned u; } v; v.f = x;
    unsigned r = v.u + 0x7fffu + ((v.u >> 16) & 1u);
    return (unsigned short)(r >> 16);
}
__device__ __forceinline__ float bf2f(unsigned short h) {
    union { unsigned u; float f; } v; v.u = ((unsigned)h) << 16;
    return v.f;
}

// ------------- x split: x[b][t][k] f32 -> Xhi/Xlo [m=t*64+b][256] bf16 -----
__global__ __launch_bounds__(256) void xsplit_k(
    const float* __restrict__ x, unsigned short* __restrict__ Xhi,
    unsigned short* __restrict__ Xlo)
{
    const int idx = blockIdx.x * 256 + threadIdx.x;   // 524288 total
    const int m = idx >> 5, kq = idx & 31;
    const int b = m & 63, t = m >> 6;
    const float* src = x + (size_t)b * 65536 + (size_t)t * 256 + kq * 8;
    short8 hv, lv;
#pragma unroll
    for (int e = 0; e < 8; ++e) {
        const float f = src[e];
        const unsigned short h = f2bf(f);
        hv[e] = (short)h;
        lv[e] = (short)f2bf(f - bf2f(h));
    }
    const size_t o = (size_t)m * 256 + kq * 8;
    *reinterpret_cast<short8*>(Xhi + o) = hv;
    *reinterpret_cast<short8*>(Xlo + o) = lv;
}

// ------------- W split+transpose: W[K][N] f32 -> Bt hi/lo [N][K] bf16 ------
__global__ __launch_bounds__(256) void bsplitN_k(
    const float* __restrict__ W, unsigned short* __restrict__ Bhi,
    unsigned short* __restrict__ Blo, int K, int N)
{
    __shared__ float tl[32][65];
    const int k0 = blockIdx.x * 32, n0 = blockIdx.y * 64;
    const int tid = threadIdx.x;
    {
        const int kk = tid >> 3, nq = tid & 7;
#pragma unroll
        for (int j = 0; j < 2; ++j) {
            const float4 v = *reinterpret_cast<const float4*>(
                &W[(size_t)(k0 + kk) * N + n0 + nq * 8 + j * 4]);
            tl[kk][nq * 8 + j * 4 + 0] = v.x; tl[kk][nq * 8 + j * 4 + 1] = v.y;
            tl[kk][nq * 8 + j * 4 + 2] = v.z; tl[kk][nq * 8 + j * 4 + 3] = v.w;
        }
    }
    __syncthreads();
    const int n = tid >> 2, kq = tid & 3;
    short8 hv, lv;
#pragma unroll
    for (int j = 0; j < 8; ++j) {
        const float xv = tl[kq * 8 + j][n];
        const unsigned short h = f2bf(xv);
        hv[j] = (short)h;
        lv[j] = (short)f2bf(xv - bf2f(h));
    }
    const size_t o = (size_t)(n0 + n) * K + k0 + kq * 8;
    *reinterpret_cast<short8*>(&Bhi[o]) = hv;
    *reinterpret_cast<short8*>(&Blo[o]) = lv;
}

// ------------- enc MFMA GEMM: Ef = PReLU(X @ Wenc + benc), granule out -----
__global__ __launch_bounds__(256) void enc_mfma_k(
    const unsigned short* __restrict__ Ahi, const unsigned short* __restrict__ Alo,
    const unsigned short* __restrict__ Bhi, const unsigned short* __restrict__ Blo,
    unsigned short* __restrict__ Ef, const float* __restrict__ benc,
    const float* __restrict__ alphap)
{
    __shared__ float smemf[10240];                       // 40 KB
    unsigned short* const smemh = (unsigned short*)smemf;
    unsigned short* const As0 = smemh;
    unsigned short* const As1 = smemh + 5120;
    unsigned short* const Bs0 = smemh + 10240;
    unsigned short* const Bs1 = smemh + 15360;

    const int tid = threadIdx.x;
    const int lane = tid & 63, wid = tid >> 6;
    const int wm = wid >> 1, wn = wid & 1;
    const int m0 = blockIdx.y * 128;
    const int n0 = blockIdx.x * 128;
    const int K = 256;

    f32x4 acc[4][4] = {};

    const int sr = tid & 127;
    const int spl = tid >> 7;
    const unsigned short* Ag = (spl ? Alo : Ahi) + (size_t)(m0 + sr) * K;
    const unsigned short* Bg = (spl ? Blo : Bhi) + (size_t)(n0 + sr) * K;
    unsigned short* Asw = (spl ? As1 : As0) + sr * 40;
    unsigned short* Bsw = (spl ? Bs1 : Bs0) + sr * 40;
    const int sw = sr & 3;

    const int kg = lane >> 4;
    const int fr = lane & 15;

    for (int k0 = 0; k0 < K; k0 += 32) {
        short8 av[4], bv[4];
#pragma unroll
        for (int c = 0; c < 4; ++c) {
            av[c] = LD8(Ag + k0 + c * 8);
            bv[c] = LD8(Bg + k0 + c * 8);
        }
        __syncthreads();
#pragma unroll
        for (int c = 0; c < 4; ++c) {
            *reinterpret_cast<short8*>(Asw + ((c ^ sw) * 8)) = av[c];
            *reinterpret_cast<short8*>(Bsw + ((c ^ sw) * 8)) = bv[c];
        }
        __syncthreads();

        short8 af[2][4], bf[2][4];
#pragma unroll
        for (int i = 0; i < 4; ++i) {
            const int ra = wm * 64 + i * 16 + fr;
            const int rb = wn * 64 + i * 16 + fr;
            af[0][i] = LD8(As0 + ra * 40 + ((kg ^ (ra & 3)) * 8));
            af[1][i] = LD8(As1 + ra * 40 + ((kg ^ (ra & 3)) * 8));
            bf[0][i] = LD8(Bs0 + rb * 40 + ((kg ^ (rb & 3)) * 8));
            bf[1][i] = LD8(Bs1 + rb * 40 + ((kg ^ (rb & 3)) * 8));
        }
#pragma unroll
        for (int i = 0; i < 4; ++i)
#pragma unroll
            for (int j = 0; j < 4; ++j) {
                acc[i][j] = __builtin_amdgcn_mfma_f32_16x16x32_bf16(
                    af[0][i], bf[0][j], acc[i][j], 0, 0, 0);
                acc[i][j] = __builtin_amdgcn_mfma_f32_16x16x32_bf16(
                    af[0][i], bf[1][j], acc[i][j], 0, 0, 0);
                acc[i][j] = __builtin_amdgcn_mfma_f32_16x16x32_bf16(
                    af[1][i], bf[0][j], acc[i][j], 0, 0, 0);
            }
    }
    __syncthreads();                                     // staging LDS dead

    float* slab = smemf + wid * 1040;
    const int t = (m0 >> 6) + wm;
    const int fq = lane >> 4;
    const float alpha = alphap[0];
#pragma unroll 1
    for (int j = 0; j < 4; ++j) {
#pragma unroll
        for (int i = 0; i < 4; ++i)
#pragma unroll
            for (int rr = 0; rr < 4; ++rr)
                slab[fr * 65 + i * 16 + fq * 4 + rr] = acc[i][j][rr];
        __syncthreads();
        const int b = lane;
        const int nj = b >> 4;
#pragma unroll
        for (int ng = 0; ng < 4; ++ng) {
            const int n = n0 + wn * 64 + j * 16 + ng * 4;
            unsigned short hs[4], ls[4];
#pragma unroll
            for (int v = 0; v < 4; ++v) {
                float f = slab[(ng * 4 + v) * 65 + b] + benc[n + v];
                f = (f >= 0.f) ? f : alpha * f;
                hs[v] = f2bf(f);
                ls[v] = f2bf(f - bf2f(hs[v]));
            }
            uint2 hp, lp;
            hp.x = (unsigned)hs[0] | ((unsigned)hs[1] << 16);
            hp.y = (unsigned)hs[2] | ((unsigned)hs[3] << 16);
            lp.x = (unsigned)ls[0] | ((unsigned)ls[1] << 16);
            lp.y = (unsigned)ls[2] | ((unsigned)ls[3] << 16);
            const int s = n >> 5, kgn = (n >> 3) & 3, e0 = n & 7;
            const int ln = (b & 15) + 16 * kgn;
            const size_t base =
                ((((size_t)t * 32 + s) * 4 + nj) * 64 + ln) * 8 + e0;
            *reinterpret_cast<uint2*>(Ef + base) = hp;
            *reinterpret_cast<uint2*>(Ef + base + 32768) = lp;
        }
        __syncthreads();
    }
}

// ------------- weight prep: frag-order split planes, 4-col blocks ----------
// Wf[lb(256)][p][s][lane][8]; source col j = g*1024 + lb*4 + c, row k.
// rloc = g*4+c (<16), lane = rloc + 16*kg. Wa k<1024, Wb k>=1024. NS = K/32.
__global__ __launch_bounds__(256) void wprep4_k(
    const float* __restrict__ Wa, const float* __restrict__ Wb,
    unsigned short* __restrict__ Wf, int NS)
{
    __shared__ float tl[32][65];
    const int k0 = blockIdx.x * 32, j0 = blockIdx.y * 64;
    const int tid = threadIdx.x;
    {
        const int kk = tid >> 3, jq = tid & 7;
        const int k = k0 + kk;
        const float* src = (k < 1024) ? &Wa[(size_t)k * 4096]
                                      : &Wb[(size_t)(k - 1024) * 4096];
#pragma unroll
        for (int h = 0; h < 2; ++h) {
            const float4 v = *reinterpret_cast<const float4*>(
                &src[j0 + jq * 8 + h * 4]);
            tl[kk][jq * 8 + h * 4 + 0] = v.x; tl[kk][jq * 8 + h * 4 + 1] = v.y;
            tl[kk][jq * 8 + h * 4 + 2] = v.z; tl[kk][jq * 8 + h * 4 + 3] = v.w;
        }
    }
    __syncthreads();
    const int j = tid >> 2, kg = tid & 3;
    const int jg = j0 + j;
    const int g = jg >> 10, cc = jg & 1023;
    const int lb = cc >> 2, c = cc & 3;
    const int rloc = g * 4 + c;                           // < 16
    const int lane = rloc + 16 * kg;
    const int s = k0 >> 5;
    short8 hv, lv;
#pragma unroll
    for (int e = 0; e < 8; ++e) {
        const float x = tl[kg * 8 + e][j];
        const unsigned short h = f2bf(x);
        hv[e] = (short)h;
        lv[e] = (short)f2bf(x - bf2f(h));
    }
    const size_t oH = (((size_t)lb * 2 + 0) * NS + s) * 512 + (size_t)lane * 8;
    const size_t oL = (((size_t)lb * 2 + 1) * NS + s) * 512 + (size_t)lane * 8;
    *reinterpret_cast<short8*>(Wf + oH) = hv;
    *reinterpret_cast<short8*>(Wf + oL) = lv;
}

// ------------- h split init: hrow fp32 [64][1024] -> granule slot ----------
__global__ __launch_bounds__(256) void hsplit_k(
    const float* __restrict__ hrow, unsigned short* __restrict__ dst)
{
    const int idx = blockIdx.x * 256 + threadIdx.x;   // 8192 total
    const int b = idx >> 7, gc = idx & 127;
    const int k = gc * 8;
    short8 hv, lv;
#pragma unroll
    for (int e = 0; e < 8; ++e) {
        const float x = hrow[(size_t)b * 1024 + k + e];
        const unsigned short h = f2bf(x);
        hv[e] = (short)h;
        lv[e] = (short)f2bf(x - bf2f(h));
    }
    const int s = k >> 5, kg = (k >> 3) & 3, nj = b >> 4;
    const int l = (b & 15) + 16 * kg;
    const size_t oH = (((size_t)(0 * 32 + s) * 4 + nj) * 64 + l) * 8;
    const size_t oL = (((size_t)(1 * 32 + s) * 4 + nj) * 64 + l) * 8;
    *reinterpret_cast<short8*>(dst + oH) = hv;
    *reinterpret_cast<short8*>(dst + oL) = lv;
}

// ------------- permuted bias sum: out[lb*16+g*4+c] = bx[j]+bh[j] -----------
__global__ __launch_bounds__(256) void bsum4_k(
    const float* __restrict__ bx, const float* __restrict__ bh,
    float* __restrict__ out)
{
    const int r = blockIdx.x * 256 + threadIdx.x;     // 4096
    const int lb = r >> 4, rl = r & 15;
    const int g = rl >> 2, c = rl & 3;
    const int j = g * 1024 + lb * 4 + c;
    out[r] = bx[j] + bh[j];
}

// ---------------- fused dual-layer LSTM, paired-layer blocks ---------------
// bar: per-block flags at bid*32 uints (512 x 128B).
__global__ __launch_bounds__(256, 2) void fused_lstm_k(
    const unsigned short* __restrict__ Ef,
    const unsigned short* __restrict__ Wf0,
    const unsigned short* __restrict__ Wf1,
    unsigned short* __restrict__ Y0, unsigned short* __restrict__ H1,
    const float* __restrict__ c0, const float* __restrict__ bsum0p,
    const float* __restrict__ bsum1p, float* __restrict__ hst1,
    unsigned* bar)
{
    __shared__ float Pred[4][16][66];
    __shared__ unsigned short hasmH[64][4];
    __shared__ unsigned short hasmL[64][4];

    const int tid = threadIdx.x;
    const int lane = tid & 63;                 // batch row for MFMA frags
    const int w = tid >> 6;                    // wave id 0..3
    const int bid = blockIdx.x;
    const int layer = bid >> 8;
    const int lb = bid & 255;

    const int NS = layer ? 64 : 48;            // K/32
    const int nSub = layer ? 16 : 12;          // 8 own + {8 y0 | 4 E}

    const unsigned short* Wf = layer ? Wf1 : Wf0;
    const unsigned short* wB =
        Wf + (size_t)lb * 2 * NS * 512 + (size_t)lane * 8;

    // ---- register-resident weights (loaded once) ----
    short8 wHi[16], wLo[16];
#pragma unroll
    for (int i = 0; i < 16; ++i)
        if (i < nSub) {
            const int s = (i < 8)
                ? (w * 8 + i)
                : (32 + (layer ? w * 8 : w * 4) + (i - 8));
            wHi[i] = LD8(wB + (size_t)s * 512);
            wLo[i] = LD8(wB + (size_t)(NS + s) * 512);
        }

    // activation mapping: thread -> (b = lane, col = w), 4 cols/block
    const int col = w;
    float c_ = c0[(size_t)layer * 65536 + (size_t)lane * 1024 + lb * 4 + col];
    const float* bsB = layer ? bsum1p : bsum0p;
    float bs[4];
#pragma unroll
    for (int g = 0; g < 4; ++g) bs[g] = bsB[lb * 16 + g * 4 + col];

#define MM(nj, HH, HL)                                                         \
    acc[nj] = __builtin_amdgcn_mfma_f32_16x16x32_bf16(wHi[i], HH, acc[nj], 0, 0, 0); \
    acc[nj] = __builtin_amdgcn_mfma_f32_16x16x32_bf16(wHi[i], HL, acc[nj], 0, 0, 0); \
    acc[nj] = __builtin_amdgcn_mfma_f32_16x16x32_bf16(wLo[i], HH, acc[nj], 0, 0, 0);
#define SUBTILE(hp, po)                                                        \
    {                                                                          \
        const short8 h0v = LD8(hp),        h1v = LD8(hp + 512);                \
        const short8 h2v = LD8(hp + 1024), h3v = LD8(hp + 1536);               \
        const short8 l0v = LD8(hp + po),        l1v = LD8(hp + po + 512);      \
        const short8 l2v = LD8(hp + po + 1024), l3v = LD8(hp + po + 1536);     \
        MM(0, h0v, l0v)  MM(1, h1v, l1v)  MM(2, h2v, l2v)  MM(3, h3v, l3v)     \
    }
    // 64-lane poll of 64 producer flags, then compiler barrier.
#define WPOLL(baseIdx, need)                                                   \
    {                                                                          \
        unsigned* p = bar + (size_t)((baseIdx) + lane) * 32;                   \
        while (__hip_atomic_load(p, __ATOMIC_RELAXED,                          \
                                 __HIP_MEMORY_SCOPE_AGENT) < (need))           \
            __builtin_amdgcn_s_sleep(1);                                       \
        __builtin_amdgcn_wave_barrier();                                       \
        asm volatile("" ::: "memory");                                         \
    }

    for (int r = 1; r <= 257; ++r) {
        const bool act = layer ? (r >= 2) : (r <= 256);
        if (act) {
            const int t = layer ? r - 2 : r - 1;
            const unsigned short* hOwn =
                (layer ? H1 : Y0) + (size_t)t * 131072 + (size_t)lane * 8;
            const unsigned short* hCross = layer
                ? Y0 + (size_t)(t + 1) * 131072 + (size_t)lane * 8
                : Ef + (size_t)t * 65536 + (size_t)lane * 8;
            const int poCross = layer ? 65536 : 32768;

            f32x4 acc[4] = {};

            // cross part (L0: E, no dep; L1: y0 slot t+1, L0 flags >= r-1)
            if (layer) WPOLL(w * 64, (unsigned)(r - 1))
#pragma unroll
            for (int i = 8; i < 16; ++i)
                if (i < nSub) {
                    const int cs = (layer ? w * 8 : w * 4) + (i - 8);
                    const unsigned short* hp = hCross + (size_t)cs * 2048;
                    SUBTILE(hp, poCross)
                }

            // own part (own-layer producer flags >= r-1)
            if (r >= 2) WPOLL((layer ? 256 : 0) + w * 64, (unsigned)(r - 1))
#pragma unroll
            for (int i = 0; i < 8; ++i) {
                const unsigned short* hp = hOwn + (size_t)(w * 8 + i) * 2048;
                SUBTILE(hp, 65536)
            }

            // k-split partials: row = (lane>>4)*4+rr, col = nj*16+(lane&15)
            {
                const int rq = (lane >> 4) * 4, cq = lane & 15;
#pragma unroll
                for (int nj = 0; nj < 4; ++nj)
#pragma unroll
                    for (int rr = 0; rr < 4; ++rr)
                        Pred[w][rq + rr][nj * 16 + cq] = acc[nj][rr];
            }
            __syncthreads();

            // activation: thread (b = lane, col = w)
            {
                float p[4];
#pragma unroll
                for (int g = 0; g < 4; ++g) {
                    const int row = g * 4 + col;
                    p[g] = Pred[0][row][lane] + Pred[1][row][lane] +
                           Pred[2][row][lane] + Pred[3][row][lane] + bs[g];
                }
                const float fg = sigmoidf_(p[0]);
                const float ig = sigmoidf_(p[1]);
                const float gg = tanhf(p[2]);
                const float og = sigmoidf_(p[3]);
                c_ = fmaf(fg, c_, ig * gg);
                const float h = og * tanhf(c_);
                const unsigned short hh = f2bf(h);
                hasmH[lane][col] = hh;
                hasmL[lane][col] = f2bf(h - bf2f(hh));
                if (layer && r == 257)
                    hst1[(size_t)(lb * 4 + col) * 64 + lane] = h;
            }
            __syncthreads();

            // wave-0-only: granule stores (8B halves) + drain + flag publish.
            // waves 1-3 run ahead into next round (hazards ordered by the
            // next round's post-Pred __syncthreads).
            if (w == 0) {
                unsigned short* hw =
                    (layer ? H1 : Y0) + (size_t)(t + 1) * 131072;
                const int s = lb >> 3, kg2 = (lb >> 1) & 3;
                const int e0 = (lb & 1) * 4;
                const int b = lane;
                const size_t offH =
                    (((size_t)s * 4 + (b >> 4)) * 64 +
                     ((b & 15) + 16 * kg2)) * 8 + e0;
                __hip_atomic_store(
                    reinterpret_cast<unsigned long long*>(hw + offH),
                    *reinterpret_cast<const unsigned long long*>(&hasmH[b][0]),
                    __ATOMIC_RELAXED, __HIP_MEMORY_SCOPE_AGENT);
                __hip_atomic_store(
                    reinterpret_cast<unsigned long long*>(hw + offH + 65536),
                    *reinterpret_cast<const unsigned long long*>(&hasmL[b][0]),
                    __ATOMIC_RELAXED, __HIP_MEMORY_SCOPE_AGENT);
                if (r <= 256) {
                    asm volatile("s_waitcnt vmcnt(0)" ::: "memory");
                    __builtin_amdgcn_wave_barrier();
                    if (lane == 0)
                        __hip_atomic_store(bar + (size_t)bid * 32, (unsigned)r,
                                           __ATOMIC_RELAXED,
                                           __HIP_MEMORY_SCOPE_AGENT);
                }
            }
        } else {
            // inactive round (L1 r=1): still publish so consumers can pass
            if (r <= 256 && tid == 0)
                __hip_atomic_store(bar + (size_t)bid * 32, (unsigned)r,
                                   __ATOMIC_RELAXED, __HIP_MEMORY_SCOPE_AGENT);
        }
    }
#undef WPOLL
#undef SUBTILE
#undef MM
}

// ---------------- classifier ------------------------------------------------
__global__ __launch_bounds__(256) void cls_k(
    const float* __restrict__ hfin, const float* __restrict__ Wc,
    const float* __restrict__ bcls, float* __restrict__ out)
{
    __shared__ float red[4][64];
    const int n = blockIdx.x;
    const int lane = threadIdx.x & 63, w = threadIdx.x >> 6;
    float acc = 0.f;
    for (int k = w * 256; k < w * 256 + 256; ++k)
        acc = fmaf(hfin[k * 64 + lane], Wc[k * 10 + n], acc);
    red[w][lane] = acc;
    __syncthreads();
    if (w == 0) {
        out[lane * 10 + n] = red[0][lane] + red[1][lane] + red[2][lane] +
                             red[3][lane] + bcls[n];
    }
}

extern "C" void kernel_launch(void* const* d_in, const int* in_sizes, int n_in,
                              void* d_out, int out_size, void* d_ws,
                              size_t ws_size, hipStream_t stream)
{
    const float* x    = (const float*)d_in[0];
    const float* h0   = (const float*)d_in[1];
    const float* c0   = (const float*)d_in[2];
    const float* Wenc = (const float*)d_in[3];
    const float* benc = (const float*)d_in[4];
    const float* alpha= (const float*)d_in[5];
    const float* Wx0  = (const float*)d_in[6];
    const float* bx0  = (const float*)d_in[7];
    const float* Wh0  = (const float*)d_in[8];
    const float* bh0  = (const float*)d_in[9];
    const float* Wx1  = (const float*)d_in[10];
    const float* bx1  = (const float*)d_in[11];
    const float* Wh1  = (const float*)d_in[12];
    const float* bh1  = (const float*)d_in[13];
    const float* Wcls = (const float*)d_in[14];
    const float* bcls = (const float*)d_in[15];
    float* out = (float*)d_out;

    // Workspace plan (floats): ~61.3M floats = 245 MB (budget >= 279 MB).
    float* ws = (float*)d_ws;
    size_t off = 0;
    unsigned short* Ef   = (unsigned short*)(ws + off); off += 8388608;   // 16.7M sh
    unsigned short* Wf0  = (unsigned short*)(ws + off); off += 6291456;   // 12.6M sh
    unsigned short* Wf1  = (unsigned short*)(ws + off); off += 8388608;   // 16.7M sh
    unsigned short* Y0   = (unsigned short*)(ws + off); off += 16842752;  // 257 slots
    unsigned short* H1   = (unsigned short*)(ws + off); off += 16842752;  // 257 slots
    unsigned short* Xhi  = (unsigned short*)(ws + off); off += 2097152;
    unsigned short* Xlo  = (unsigned short*)(ws + off); off += 2097152;
    unsigned short* WeThi= (unsigned short*)(ws + off); off += 65536;
    unsigned short* WeTlo= (unsigned short*)(ws + off); off += 65536;
    float* bsum0p = ws + off; off += 4096;
    float* bsum1p = ws + off; off += 4096;
    float* hst1   = ws + off; off += 65536;
    unsigned* bars = (unsigned*)(ws + off); off += 16384;   // 64 KB flags

    (void)hipMemsetAsync(bars, 0, 65536, stream);

    // prologue (input-only deps)
    xsplit_k<<<2048, 256, 0, stream>>>(x, Xhi, Xlo);
    bsplitN_k<<<dim3(8, 8), 256, 0, stream>>>(Wenc, WeThi, WeTlo, 256, 512);
    enc_mfma_k<<<dim3(4, 128), 256, 0, stream>>>(
        Xhi, Xlo, WeThi, WeTlo, Ef, benc, alpha);
    wprep4_k<<<dim3(48, 64), 256, 0, stream>>>(Wh0, Wx0, Wf0, 48);
    wprep4_k<<<dim3(64, 64), 256, 0, stream>>>(Wh1, Wx1, Wf1, 64);
    hsplit_k<<<32, 256, 0, stream>>>(h0, Y0);                // h0_init -> slot 0
    hsplit_k<<<32, 256, 0, stream>>>(h0 + 65536, H1);        // h1_init -> slot 0
    bsum4_k<<<16, 256, 0, stream>>>(bx0, bh0, bsum0p);
    bsum4_k<<<16, 256, 0, stream>>>(bx1, bh1, bsum1p);

    // fused dual-layer LSTM, paired-layer blocks (257 rounds)
    fused_lstm_k<<<512, 256, 0, stream>>>(Ef, Wf0, Wf1, Y0, H1, c0,
                                          bsum0p, bsum1p, hst1, bars);

    // classifier from layer-1 final h ([k][b])
    cls_k<<<dim3(10), 256, 0, stream>>>(hst1, Wcls, bcls, out);
}

// Round 14
// 2016.875 us; speedup vs baseline: 1.9827x; 1.9827x over previous
//
#include <hip/hip_runtime.h>
#include <hip/hip_bf16.h>
#include <cstddef>

// ---------------------------------------------------------------------------
// B=64, S=256, W=256, E=512, HID=1024, L=2, NCLS=10
// xsplit + WencT split -> enc MFMA GEMM (3-pass split-bf16, granule epilogue)
// -> ONE fused dual-layer LSTM, register-resident weights, PER-WAVE p2p flag
// sync. Round-14 delta vs round-12: layer 1's two serial polls (cross L0,
// own L1) merged into ONE concurrent 32-lane poll at round top -> one
// coherence-point load latency instead of two.
//   256 blocks x 512 threads. blocks 0..127 = layer 0 (K=1536, [Wh0;Wx0]);
//   blocks 128..255 = layer 1 (K=2048, [Wh1;Wx1]).
//   State: Y0[0..256] / H1[0..256] write-once slot arrays, write-through 8B
//   agent atomics. Flags: flag[bid] = r after block-wide store drain.
//   Wave w own-h k-range = [w*128,(w+1)*128) -> producers w*16..w*16+15.
//   Fence-free: consumed lines are write-once, read only after producer's
//   flag (which follows its vmcnt drain), never locally cached earlier.
// -> classifier.
// Fragment layouts (HW-validated rounds 4/6..12, absmax 0.0):
//   A/B operand: lane = (row&15) + 16*kg holds 8 values [row][k0+kg*8 .. +7]
//   D: row = mi*16 + (lane>>4)*4 + rr, col = nj*16 + (lane&15)
// Granule layouts (16B per lane):
//   W:  Wf[lb][plane][s][mi][lane][8]
//   h slot: [plane][s(32)][nj][lane][8] (plane stride 65536 sh, slot 131072)
//   E:  Ef[t][plane][s(16)][nj][lane][8] (plane stride 32768 sh)
// Row permutation: gate row j = g*1024 + lb*8 + c -> block lb, rloc = g*8+c.
// Workspace ~245 MB (known-good budget >= 279 MB).
// ---------------------------------------------------------------------------

using short8 = __attribute__((ext_vector_type(8))) short;
using f32x4  = __attribute__((ext_vector_type(4))) float;

#define LD8(p) (*reinterpret_cast<const short8*>(p))

__device__ __forceinline__ float sigmoidf_(float x) {
    return 1.f / (1.f + __expf(-x));
}
__device__ __forceinline__ unsigned short f2bf(float x) {   // RNE bf16
    union { float f; unsigned u; } v; v.f = x;
    unsigned r = v.u + 0x7fffu + ((v.u >> 16) & 1u);
    return (unsigned short)(r >> 16);
}
__device__ __forceinline__ float bf2f(unsigned short h) {
    union { unsigned u; float f; } v; v.u = ((unsigned)h) << 16;
    return v.f;
}

// ------------- x split: x[b][t][k] f32 -> Xhi/Xlo [m=t*64+b][256] bf16 -----
__global__ __launch_bounds__(256) void xsplit_k(
    const float* __restrict__ x, unsigned short* __restrict__ Xhi,
    unsigned short* __restrict__ Xlo)
{
    const int idx = blockIdx.x * 256 + threadIdx.x;   // 524288 total
    const int m = idx >> 5, kq = idx & 31;
    const int b = m & 63, t = m >> 6;
    const float* src = x + (size_t)b * 65536 + (size_t)t * 256 + kq * 8;
    short8 hv, lv;
#pragma unroll
    for (int e = 0; e < 8; ++e) {
        const float f = src[e];
        const unsigned short h = f2bf(f);
        hv[e] = (short)h;
        lv[e] = (short)f2bf(f - bf2f(h));
    }
    const size_t o = (size_t)m * 256 + kq * 8;
    *reinterpret_cast<short8*>(Xhi + o) = hv;
    *reinterpret_cast<short8*>(Xlo + o) = lv;
}

// ------------- W split+transpose: W[K][N] f32 -> Bt hi/lo [N][K] bf16 ------
__global__ __launch_bounds__(256) void bsplitN_k(
    const float* __restrict__ W, unsigned short* __restrict__ Bhi,
    unsigned short* __restrict__ Blo, int K, int N)
{
    __shared__ float tl[32][65];
    const int k0 = blockIdx.x * 32, n0 = blockIdx.y * 64;
    const int tid = threadIdx.x;
    {
        const int kk = tid >> 3, nq = tid & 7;
#pragma unroll
        for (int j = 0; j < 2; ++j) {
            const float4 v = *reinterpret_cast<const float4*>(
                &W[(size_t)(k0 + kk) * N + n0 + nq * 8 + j * 4]);
            tl[kk][nq * 8 + j * 4 + 0] = v.x; tl[kk][nq * 8 + j * 4 + 1] = v.y;
            tl[kk][nq * 8 + j * 4 + 2] = v.z; tl[kk][nq * 8 + j * 4 + 3] = v.w;
        }
    }
    __syncthreads();
    const int n = tid >> 2, kq = tid & 3;
    short8 hv, lv;
#pragma unroll
    for (int j = 0; j < 8; ++j) {
        const float xv = tl[kq * 8 + j][n];
        const unsigned short h = f2bf(xv);
        hv[j] = (short)h;
        lv[j] = (short)f2bf(xv - bf2f(h));
    }
    const size_t o = (size_t)(n0 + n) * K + k0 + kq * 8;
    *reinterpret_cast<short8*>(&Bhi[o]) = hv;
    *reinterpret_cast<short8*>(&Blo[o]) = lv;
}

// ------------- enc MFMA GEMM: Ef = PReLU(X @ Wenc + benc), granule out -----
__global__ __launch_bounds__(256) void enc_mfma_k(
    const unsigned short* __restrict__ Ahi, const unsigned short* __restrict__ Alo,
    const unsigned short* __restrict__ Bhi, const unsigned short* __restrict__ Blo,
    unsigned short* __restrict__ Ef, const float* __restrict__ benc,
    const float* __restrict__ alphap)
{
    __shared__ float smemf[10240];                       // 40 KB
    unsigned short* const smemh = (unsigned short*)smemf;
    unsigned short* const As0 = smemh;
    unsigned short* const As1 = smemh + 5120;
    unsigned short* const Bs0 = smemh + 10240;
    unsigned short* const Bs1 = smemh + 15360;

    const int tid = threadIdx.x;
    const int lane = tid & 63, wid = tid >> 6;
    const int wm = wid >> 1, wn = wid & 1;
    const int m0 = blockIdx.y * 128;
    const int n0 = blockIdx.x * 128;
    const int K = 256;

    f32x4 acc[4][4] = {};

    const int sr = tid & 127;
    const int spl = tid >> 7;
    const unsigned short* Ag = (spl ? Alo : Ahi) + (size_t)(m0 + sr) * K;
    const unsigned short* Bg = (spl ? Blo : Bhi) + (size_t)(n0 + sr) * K;
    unsigned short* Asw = (spl ? As1 : As0) + sr * 40;
    unsigned short* Bsw = (spl ? Bs1 : Bs0) + sr * 40;
    const int sw = sr & 3;

    const int kg = lane >> 4;
    const int fr = lane & 15;

    for (int k0 = 0; k0 < K; k0 += 32) {
        short8 av[4], bv[4];
#pragma unroll
        for (int c = 0; c < 4; ++c) {
            av[c] = LD8(Ag + k0 + c * 8);
            bv[c] = LD8(Bg + k0 + c * 8);
        }
        __syncthreads();
#pragma unroll
        for (int c = 0; c < 4; ++c) {
            *reinterpret_cast<short8*>(Asw + ((c ^ sw) * 8)) = av[c];
            *reinterpret_cast<short8*>(Bsw + ((c ^ sw) * 8)) = bv[c];
        }
        __syncthreads();

        short8 af[2][4], bf[2][4];
#pragma unroll
        for (int i = 0; i < 4; ++i) {
            const int ra = wm * 64 + i * 16 + fr;
            const int rb = wn * 64 + i * 16 + fr;
            af[0][i] = LD8(As0 + ra * 40 + ((kg ^ (ra & 3)) * 8));
            af[1][i] = LD8(As1 + ra * 40 + ((kg ^ (ra & 3)) * 8));
            bf[0][i] = LD8(Bs0 + rb * 40 + ((kg ^ (rb & 3)) * 8));
            bf[1][i] = LD8(Bs1 + rb * 40 + ((kg ^ (rb & 3)) * 8));
        }
#pragma unroll
        for (int i = 0; i < 4; ++i)
#pragma unroll
            for (int j = 0; j < 4; ++j) {
                acc[i][j] = __builtin_amdgcn_mfma_f32_16x16x32_bf16(
                    af[0][i], bf[0][j], acc[i][j], 0, 0, 0);
                acc[i][j] = __builtin_amdgcn_mfma_f32_16x16x32_bf16(
                    af[0][i], bf[1][j], acc[i][j], 0, 0, 0);
                acc[i][j] = __builtin_amdgcn_mfma_f32_16x16x32_bf16(
                    af[1][i], bf[0][j], acc[i][j], 0, 0, 0);
            }
    }
    __syncthreads();                                     // staging LDS dead

    // Epilogue: per-wave slab [16 n][65 m] -> PReLU+split -> Ef granules.
    float* slab = smemf + wid * 1040;
    const int t = (m0 >> 6) + wm;                        // this wave's t
    const int fq = lane >> 4;
    const float alpha = alphap[0];
#pragma unroll 1
    for (int j = 0; j < 4; ++j) {
#pragma unroll
        for (int i = 0; i < 4; ++i)
#pragma unroll
            for (int rr = 0; rr < 4; ++rr)
                slab[fr * 65 + i * 16 + fq * 4 + rr] = acc[i][j][rr];
        __syncthreads();
        const int b = lane;                              // m_local = batch
        const int nj = b >> 4;
#pragma unroll
        for (int ng = 0; ng < 4; ++ng) {
            const int n = n0 + wn * 64 + j * 16 + ng * 4;
            unsigned short hs[4], ls[4];
#pragma unroll
            for (int v = 0; v < 4; ++v) {
                float f = slab[(ng * 4 + v) * 65 + b] + benc[n + v];
                f = (f >= 0.f) ? f : alpha * f;
                hs[v] = f2bf(f);
                ls[v] = f2bf(f - bf2f(hs[v]));
            }
            uint2 hp, lp;
            hp.x = (unsigned)hs[0] | ((unsigned)hs[1] << 16);
            hp.y = (unsigned)hs[2] | ((unsigned)hs[3] << 16);
            lp.x = (unsigned)ls[0] | ((unsigned)ls[1] << 16);
            lp.y = (unsigned)ls[2] | ((unsigned)ls[3] << 16);
            const int s = n >> 5, kgn = (n >> 3) & 3, e0 = n & 7;
            const int ln = (b & 15) + 16 * kgn;
            const size_t base =
                ((((size_t)t * 32 + s) * 4 + nj) * 64 + ln) * 8 + e0;
            *reinterpret_cast<uint2*>(Ef + base) = hp;
            *reinterpret_cast<uint2*>(Ef + base + 32768) = lp;
        }
        __syncthreads();
    }
}

// ------------- weight prep: frag-order split planes ------------------------
__global__ __launch_bounds__(256) void wprep_k(
    const float* __restrict__ Wa, const float* __restrict__ Wb,
    unsigned short* __restrict__ Wf, int NS)
{
    __shared__ float tl[32][65];
    const int k0 = blockIdx.x * 32, j0 = blockIdx.y * 64;
    const int tid = threadIdx.x;
    {
        const int kk = tid >> 3, jq = tid & 7;
        const int k = k0 + kk;
        const float* src = (k < 1024) ? &Wa[(size_t)k * 4096]
                                      : &Wb[(size_t)(k - 1024) * 4096];
#pragma unroll
        for (int h = 0; h < 2; ++h) {
            const float4 v = *reinterpret_cast<const float4*>(
                &src[j0 + jq * 8 + h * 4]);
            tl[kk][jq * 8 + h * 4 + 0] = v.x; tl[kk][jq * 8 + h * 4 + 1] = v.y;
            tl[kk][jq * 8 + h * 4 + 2] = v.z; tl[kk][jq * 8 + h * 4 + 3] = v.w;
        }
    }
    __syncthreads();
    const int j = tid >> 2, kg = tid & 3;
    const int jg = j0 + j;
    const int g = jg >> 10, cc = jg & 1023;
    const int lb = cc >> 3, c = cc & 7;
    const int rloc = g * 8 + c;
    const int mi = rloc >> 4, r16 = rloc & 15;
    const int lane = r16 + 16 * kg;
    const int s = k0 >> 5;
    short8 hv, lv;
#pragma unroll
    for (int e = 0; e < 8; ++e) {
        const float x = tl[kg * 8 + e][j];
        const unsigned short h = f2bf(x);
        hv[e] = (short)h;
        lv[e] = (short)f2bf(x - bf2f(h));
    }
    const size_t oH = ((((size_t)lb * 2 + 0) * NS + s) * 2 + mi) * 512 + (size_t)lane * 8;
    const size_t oL = ((((size_t)lb * 2 + 1) * NS + s) * 2 + mi) * 512 + (size_t)lane * 8;
    *reinterpret_cast<short8*>(Wf + oH) = hv;
    *reinterpret_cast<short8*>(Wf + oL) = lv;
}

// ------------- h split init: hrow fp32 [64][1024] -> granule slot ----------
__global__ __launch_bounds__(256) void hsplit_k(
    const float* __restrict__ hrow, unsigned short* __restrict__ dst)
{
    const int idx = blockIdx.x * 256 + threadIdx.x;   // 8192 total
    const int b = idx >> 7, gc = idx & 127;
    const int k = gc * 8;
    short8 hv, lv;
#pragma unroll
    for (int e = 0; e < 8; ++e) {
        const float x = hrow[(size_t)b * 1024 + k + e];
        const unsigned short h = f2bf(x);
        hv[e] = (short)h;
        lv[e] = (short)f2bf(x - bf2f(h));
    }
    const int s = k >> 5, kg = (k >> 3) & 3, nj = b >> 4;
    const int l = (b & 15) + 16 * kg;
    const size_t oH = (((size_t)(0 * 32 + s) * 4 + nj) * 64 + l) * 8;
    const size_t oL = (((size_t)(1 * 32 + s) * 4 + nj) * 64 + l) * 8;
    *reinterpret_cast<short8*>(dst + oH) = hv;
    *reinterpret_cast<short8*>(dst + oL) = lv;
}

// ------------- permuted bias sum: out[lb*32+g*8+c] = bx[j]+bh[j] -----------
__global__ __launch_bounds__(256) void bsum_k(
    const float* __restrict__ bx, const float* __restrict__ bh,
    float* __restrict__ out)
{
    const int r = blockIdx.x * 256 + threadIdx.x;     // 4096
    const int lb = r >> 5, rl = r & 31;
    const int g = rl >> 3, c = rl & 7;
    const int j = g * 1024 + lb * 8 + c;
    out[r] = bx[j] + bh[j];
}

// ---------------- fused dual-layer LSTM, per-wave p2p flag sync ------------
// bar: per-block flags at bid*32 uints (256 x 128B).
__global__ __launch_bounds__(512, 2) void fused_lstm_k(
    const unsigned short* __restrict__ Ef,
    const unsigned short* __restrict__ Wf0,
    const unsigned short* __restrict__ Wf1,
    unsigned short* __restrict__ Y0, unsigned short* __restrict__ H1,
    const float* __restrict__ c0, const float* __restrict__ bsum0p,
    const float* __restrict__ bsum1p, float* __restrict__ hst1,
    unsigned* bar)
{
    __shared__ float Pred[8][32][66];
    __shared__ unsigned short hasmH[64][8];
    __shared__ unsigned short hasmL[64][8];

    const int tid = threadIdx.x;
    const int lane = tid & 63;                 // batch row for MFMA frags
    const int w = tid >> 6;                    // wave id 0..7
    const int bid = blockIdx.x;
    const int layer = bid >> 7;
    const int lb = bid & 127;

    const int NS = layer ? 64 : 48;            // K/32
    const int nEx = layer ? 4 : 2;             // cross subtiles per wave
    const int wNS = NS * 1024;                 // plane offset in weight shorts

    const unsigned short* Wf = layer ? Wf1 : Wf0;
    const unsigned short* wB =
        Wf + (size_t)lb * 2 * NS * 1024 + (size_t)lane * 8;

    // ---- load this wave's weight fragments into registers (once) ----
    short8 w00r[8], w01r[8], w10r[8], w11r[8];
#pragma unroll
    for (int i = 0; i < 8; ++i)
        if (i < 4 + nEx) {
            const int sg = (i < 4)
                ? (w * 4 + i)
                : (layer ? (32 + w * 4 + (i - 4)) : (32 + w * 2 + (i - 4)));
            const unsigned short* wp = wB + (size_t)sg * 1024;
            w00r[i] = LD8(wp);        w01r[i] = LD8(wp + 512);
            w10r[i] = LD8(wp + wNS);  w11r[i] = LD8(wp + wNS + 512);
        }

    // activation mapping: thread -> (b = lane, h-col = w)
    const int col = w;
    float c_ = c0[(size_t)layer * 65536 + (size_t)lane * 1024 + lb * 8 + col];
    const float* bsB = layer ? bsum1p : bsum0p;
    float bs[4];
#pragma unroll
    for (int g = 0; g < 4; ++g) bs[g] = bsB[lb * 32 + g * 8 + col];

#define MM(mi, nj, HH, HL)                                                     \
    acc[mi][nj] = __builtin_amdgcn_mfma_f32_16x16x32_bf16(                     \
        (mi) ? w01r[i] : w00r[i], HH, acc[mi][nj], 0, 0, 0);                   \
    acc[mi][nj] = __builtin_amdgcn_mfma_f32_16x16x32_bf16(                     \
        (mi) ? w01r[i] : w00r[i], HL, acc[mi][nj], 0, 0, 0);                   \
    acc[mi][nj] = __builtin_amdgcn_mfma_f32_16x16x32_bf16(                     \
        (mi) ? w11r[i] : w10r[i], HH, acc[mi][nj], 0, 0, 0);
#define SUBTILE(hp, po)                                                        \
    {                                                                          \
        const short8 h0v = LD8(hp),        h1v = LD8(hp + 512);                \
        const short8 h2v = LD8(hp + 1024), h3v = LD8(hp + 1536);               \
        const short8 l0v = LD8(hp + po),        l1v = LD8(hp + po + 512);      \
        const short8 l2v = LD8(hp + po + 1024), l3v = LD8(hp + po + 1536);     \
        MM(0, 0, h0v, l0v)  MM(0, 1, h1v, l1v)                                 \
        MM(0, 2, h2v, l2v)  MM(0, 3, h3v, l3v)                                 \
        MM(1, 0, h0v, l0v)  MM(1, 1, h1v, l1v)                                 \
        MM(1, 2, h2v, l2v)  MM(1, 3, h3v, l3v)                                 \
    }
    // wave-local poll of 16 producer flags (lanes 0..15).
#define WPOLL(baseIdx, need)                                                   \
    {                                                                          \
        if (lane < 16) {                                                       \
            unsigned* p = bar + (size_t)((baseIdx) + lane) * 32;               \
            while (__hip_atomic_load(p, __ATOMIC_RELAXED,                      \
                                     __HIP_MEMORY_SCOPE_AGENT) < (need))       \
                __builtin_amdgcn_s_sleep(1);                                   \
        }                                                                      \
        __builtin_amdgcn_wave_barrier();                                       \
        asm volatile("" ::: "memory");                                         \
    }
    // merged concurrent poll: lanes 0..15 -> baseA flags, 16..31 -> baseB.
#define WPOLL2(baseA, baseB, need)                                             \
    {                                                                          \
        if (lane < 32) {                                                       \
            const int fi = (lane < 16) ? ((baseA) + lane)                      \
                                       : ((baseB) + lane - 16);                \
            unsigned* p = bar + (size_t)fi * 32;                               \
            while (__hip_atomic_load(p, __ATOMIC_RELAXED,                      \
                                     __HIP_MEMORY_SCOPE_AGENT) < (need))       \
                __builtin_amdgcn_s_sleep(1);                                   \
        }                                                                      \
        __builtin_amdgcn_wave_barrier();                                       \
        asm volatile("" ::: "memory");                                         \
    }

    for (int r = 1; r <= 257; ++r) {
        const bool act = layer ? (r >= 2) : (r <= 256);
        if (act) {
            const int t = layer ? r - 2 : r - 1;
            const unsigned short* hOwn =
                (layer ? H1 : Y0) + (size_t)t * 131072 + (size_t)lane * 8;
            const unsigned short* hCross = layer
                ? Y0 + (size_t)(t + 1) * 131072 + (size_t)lane * 8
                : Ef + (size_t)t * 65536 + (size_t)lane * 8;
            const int poCross = layer ? 65536 : 32768;

            f32x4 acc[2][4] = {};

            // L1: ONE merged concurrent poll (cross L0 flags + own L1 flags)
            // -> single coherence-point load latency instead of two serial.
            if (layer) WPOLL2(w * 16, 128 + w * 16, (unsigned)(r - 1))
#pragma unroll
            for (int i = 4; i < 8; ++i)
                if (i < 4 + nEx) {
                    const int cs = layer ? (w * 4 + (i - 4)) : (w * 2 + (i - 4));
                    const unsigned short* hp = hCross + (size_t)cs * 2048;
                    SUBTILE(hp, poCross)
                }

            // L0 own part: poll its 16 producers (E part above had no dep)
            if (!layer && r >= 2) WPOLL(w * 16, (unsigned)(r - 1))
#pragma unroll
            for (int i = 0; i < 4; ++i) {
                const unsigned short* hp = hOwn + (size_t)(w * 4 + i) * 2048;
                SUBTILE(hp, 65536)
            }

            // k-split partials: row = mi*16+(lane>>4)*4+rr, col = nj*16+(lane&15)
            {
                const int rq = (lane >> 4) * 4, cq = lane & 15;
#pragma unroll
                for (int mi = 0; mi < 2; ++mi)
#pragma unroll
                    for (int nj = 0; nj < 4; ++nj)
#pragma unroll
                        for (int rr = 0; rr < 4; ++rr)
                            Pred[w][mi * 16 + rq + rr][nj * 16 + cq] =
                                acc[mi][nj][rr];
            }
            __syncthreads();

            // activation: thread (b = lane, col = w)
            {
                float p[4];
#pragma unroll
                for (int g = 0; g < 4; ++g) {
                    const int row = g * 8 + col;
                    float s0 = 0.f;
#pragma unroll
                    for (int ww = 0; ww < 8; ++ww)
                        s0 += Pred[ww][row][lane];
                    p[g] = s0 + bs[g];
                }
                const float fg = sigmoidf_(p[0]);
                const float ig = sigmoidf_(p[1]);
                const float gg = tanhf(p[2]);
                const float og = sigmoidf_(p[3]);
                c_ = fmaf(fg, c_, ig * gg);
                const float h = og * tanhf(c_);
                const unsigned short hh = f2bf(h);
                hasmH[lane][col] = hh;
                hasmL[lane][col] = f2bf(h - bf2f(hh));
                if (layer && r == 257)
                    hst1[(size_t)(lb * 8 + col) * 64 + lane] = h;
            }
            __syncthreads();

            // granule store -> write-once slot t+1 (write-through atomics)
            if (tid < 128) {
                const int p = tid >> 6, b = tid & 63;
                unsigned short* hw =
                    (layer ? H1 : Y0) + (size_t)(t + 1) * 131072;
                const size_t off =
                    (((size_t)(p * 32 + (lb >> 2)) * 4 + (b >> 4)) * 64 +
                     ((b & 15) + 16 * (lb & 3))) * 8;
                const unsigned long long* src =
                    reinterpret_cast<const unsigned long long*>(
                        p ? &hasmL[b][0] : &hasmH[b][0]);
                unsigned long long* dst =
                    reinterpret_cast<unsigned long long*>(hw + off);
                __hip_atomic_store(dst, src[0], __ATOMIC_RELAXED,
                                   __HIP_MEMORY_SCOPE_AGENT);
                __hip_atomic_store(dst + 1, src[1], __ATOMIC_RELAXED,
                                   __HIP_MEMORY_SCOPE_AGENT);
            }
        }

        // ---- publish flag (stores drained by the barrier's vmcnt wait) ----
        if (r <= 256) {
            __syncthreads();
            if (tid == 0)
                __hip_atomic_store(bar + (size_t)bid * 32, (unsigned)r,
                                   __ATOMIC_RELAXED, __HIP_MEMORY_SCOPE_AGENT);
        }
    }
#undef WPOLL2
#undef WPOLL
#undef SUBTILE
#undef MM
}

// ---------------- classifier ------------------------------------------------
__global__ __launch_bounds__(256) void cls_k(
    const float* __restrict__ hfin, const float* __restrict__ Wc,
    const float* __restrict__ bcls, float* __restrict__ out)
{
    __shared__ float red[4][64];
    const int n = blockIdx.x;
    const int lane = threadIdx.x & 63, w = threadIdx.x >> 6;
    float acc = 0.f;
    for (int k = w * 256; k < w * 256 + 256; ++k)
        acc = fmaf(hfin[k * 64 + lane], Wc[k * 10 + n], acc);
    red[w][lane] = acc;
    __syncthreads();
    if (w == 0) {
        out[lane * 10 + n] = red[0][lane] + red[1][lane] + red[2][lane] +
                             red[3][lane] + bcls[n];
    }
}

extern "C" void kernel_launch(void* const* d_in, const int* in_sizes, int n_in,
                              void* d_out, int out_size, void* d_ws,
                              size_t ws_size, hipStream_t stream)
{
    const float* x    = (const float*)d_in[0];
    const float* h0   = (const float*)d_in[1];
    const float* c0   = (const float*)d_in[2];
    const float* Wenc = (const float*)d_in[3];
    const float* benc = (const float*)d_in[4];
    const float* alpha= (const float*)d_in[5];
    const float* Wx0  = (const float*)d_in[6];
    const float* bx0  = (const float*)d_in[7];
    const float* Wh0  = (const float*)d_in[8];
    const float* bh0  = (const float*)d_in[9];
    const float* Wx1  = (const float*)d_in[10];
    const float* bx1  = (const float*)d_in[11];
    const float* Wh1  = (const float*)d_in[12];
    const float* bh1  = (const float*)d_in[13];
    const float* Wcls = (const float*)d_in[14];
    const float* bcls = (const float*)d_in[15];
    float* out = (float*)d_out;

    // Workspace plan (floats): ~61.2M floats = 245 MB (budget >= 279 MB).
    float* ws = (float*)d_ws;
    size_t off = 0;
    unsigned short* Ef   = (unsigned short*)(ws + off); off += 8388608;   // 16.7M sh
    unsigned short* Wf0  = (unsigned short*)(ws + off); off += 6291456;   // 12.6M sh
    unsigned short* Wf1  = (unsigned short*)(ws + off); off += 8388608;   // 16.7M sh
    unsigned short* Y0   = (unsigned short*)(ws + off); off += 16842752;  // 257 slots
    unsigned short* H1   = (unsigned short*)(ws + off); off += 16842752;  // 257 slots
    unsigned short* Xhi  = (unsigned short*)(ws + off); off += 2097152;   // 4.2M sh
    unsigned short* Xlo  = (unsigned short*)(ws + off); off += 2097152;
    unsigned short* WeThi= (unsigned short*)(ws + off); off += 65536;     // 131K sh
    unsigned short* WeTlo= (unsigned short*)(ws + off); off += 65536;
    float* bsum0p = ws + off; off += 4096;
    float* bsum1p = ws + off; off += 4096;
    float* hst1   = ws + off; off += 65536;
    unsigned* bars = (unsigned*)(ws + off); off += 8192;   // 32 KB flag area

    (void)hipMemsetAsync(bars, 0, 32768, stream);

    // prologue (input-only deps)
    xsplit_k<<<2048, 256, 0, stream>>>(x, Xhi, Xlo);
    bsplitN_k<<<dim3(8, 8), 256, 0, stream>>>(Wenc, WeThi, WeTlo, 256, 512);
    enc_mfma_k<<<dim3(4, 128), 256, 0, stream>>>(
        Xhi, Xlo, WeThi, WeTlo, Ef, benc, alpha);
    wprep_k<<<dim3(48, 64), 256, 0, stream>>>(Wh0, Wx0, Wf0, 48);
    wprep_k<<<dim3(64, 64), 256, 0, stream>>>(Wh1, Wx1, Wf1, 64);
    hsplit_k<<<32, 256, 0, stream>>>(h0, Y0);                // h0_init -> slot 0
    hsplit_k<<<32, 256, 0, stream>>>(h0 + 65536, H1);        // h1_init -> slot 0
    bsum_k<<<16, 256, 0, stream>>>(bx0, bh0, bsum0p);
    bsum_k<<<16, 256, 0, stream>>>(bx1, bh1, bsum1p);

    // fused dual-layer LSTM, per-wave p2p flag sync (257 rounds)
    fused_lstm_k<<<256, 512, 0, stream>>>(Ef, Wf0, Wf1, Y0, H1, c0,
                                          bsum0p, bsum1p, hst1, bars);

    // classifier from layer-1 final h ([k][b])
    cls_k<<<dim3(10), 256, 0, stream>>>(hst1, Wcls, bcls, out);
}

// Round 15
// 1917.098 us; speedup vs baseline: 2.0859x; 1.0520x over previous
//
#include <hip/hip_runtime.h>
#include <hip/hip_bf16.h>
#include <cstddef>

// ---------------------------------------------------------------------------
// B=64, S=256, W=256, E=512, HID=1024, L=2, NCLS=10
// REVERT to round-12 best (1911 us, absmax 0.0):
// xsplit + WencT split -> enc MFMA GEMM (3-pass split-bf16, granule epilogue)
// -> ONE fused dual-layer LSTM, register-resident weights, PER-WAVE p2p flag
// sync (wave w polls only its 16 producers; no block-wide poll joins):
//   256 blocks x 512 threads. blocks 0..127 = layer 0 (K=1536, [Wh0;Wx0]);
//   blocks 128..255 = layer 1 (K=2048, [Wh1;Wx1]).
//   State: Y0[0..256] / H1[0..256] write-once slot arrays, write-through 8B
//   agent atomics. Flags: flag[bid] = r after block-wide store drain.
//   Wave w own-h k-range = [w*128,(w+1)*128) -> producers w*16..w*16+15.
//   Fence-free: consumed lines are write-once, read only after producer's
//   flag (which follows its vmcnt drain), never locally cached earlier.
// -> classifier.
// Ceiling note: per round each block reads the full h state (~110 MB/round
// aggregate through L2, >=3.2 us at 34.5 TB/s) + serial store->flag->load
// chain (~2 us) + ~1 us compute; measured 7.5 us/round. Sync-topology and
// pairing variants all measured worse. Practical roofline for this design.
// ---------------------------------------------------------------------------

using short8 = __attribute__((ext_vector_type(8))) short;
using f32x4  = __attribute__((ext_vector_type(4))) float;

#define LD8(p) (*reinterpret_cast<const short8*>(p))

__device__ __forceinline__ float sigmoidf_(float x) {
    return 1.f / (1.f + __expf(-x));
}
__device__ __forceinline__ unsigned short f2bf(float x) {   // RNE bf16
    union { float f; unsigned u; } v; v.f = x;
    unsigned r = v.u + 0x7fffu + ((v.u >> 16) & 1u);
    return (unsigned short)(r >> 16);
}
__device__ __forceinline__ float bf2f(unsigned short h) {
    union { unsigned u; float f; } v; v.u = ((unsigned)h) << 16;
    return v.f;
}

// ------------- x split: x[b][t][k] f32 -> Xhi/Xlo [m=t*64+b][256] bf16 -----
__global__ __launch_bounds__(256) void xsplit_k(
    const float* __restrict__ x, unsigned short* __restrict__ Xhi,
    unsigned short* __restrict__ Xlo)
{
    const int idx = blockIdx.x * 256 + threadIdx.x;   // 524288 total
    const int m = idx >> 5, kq = idx & 31;
    const int b = m & 63, t = m >> 6;
    const float* src = x + (size_t)b * 65536 + (size_t)t * 256 + kq * 8;
    short8 hv, lv;
#pragma unroll
    for (int e = 0; e < 8; ++e) {
        const float f = src[e];
        const unsigned short h = f2bf(f);
        hv[e] = (short)h;
        lv[e] = (short)f2bf(f - bf2f(h));
    }
    const size_t o = (size_t)m * 256 + kq * 8;
    *reinterpret_cast<short8*>(Xhi + o) = hv;
    *reinterpret_cast<short8*>(Xlo + o) = lv;
}

// ------------- W split+transpose: W[K][N] f32 -> Bt hi/lo [N][K] bf16 ------
__global__ __launch_bounds__(256) void bsplitN_k(
    const float* __restrict__ W, unsigned short* __restrict__ Bhi,
    unsigned short* __restrict__ Blo, int K, int N)
{
    __shared__ float tl[32][65];
    const int k0 = blockIdx.x * 32, n0 = blockIdx.y * 64;
    const int tid = threadIdx.x;
    {
        const int kk = tid >> 3, nq = tid & 7;
#pragma unroll
        for (int j = 0; j < 2; ++j) {
            const float4 v = *reinterpret_cast<const float4*>(
                &W[(size_t)(k0 + kk) * N + n0 + nq * 8 + j * 4]);
            tl[kk][nq * 8 + j * 4 + 0] = v.x; tl[kk][nq * 8 + j * 4 + 1] = v.y;
            tl[kk][nq * 8 + j * 4 + 2] = v.z; tl[kk][nq * 8 + j * 4 + 3] = v.w;
        }
    }
    __syncthreads();
    const int n = tid >> 2, kq = tid & 3;
    short8 hv, lv;
#pragma unroll
    for (int j = 0; j < 8; ++j) {
        const float xv = tl[kq * 8 + j][n];
        const unsigned short h = f2bf(xv);
        hv[j] = (short)h;
        lv[j] = (short)f2bf(xv - bf2f(h));
    }
    const size_t o = (size_t)(n0 + n) * K + k0 + kq * 8;
    *reinterpret_cast<short8*>(&Bhi[o]) = hv;
    *reinterpret_cast<short8*>(&Blo[o]) = lv;
}

// ------------- enc MFMA GEMM: Ef = PReLU(X @ Wenc + benc), granule out -----
__global__ __launch_bounds__(256) void enc_mfma_k(
    const unsigned short* __restrict__ Ahi, const unsigned short* __restrict__ Alo,
    const unsigned short* __restrict__ Bhi, const unsigned short* __restrict__ Blo,
    unsigned short* __restrict__ Ef, const float* __restrict__ benc,
    const float* __restrict__ alphap)
{
    __shared__ float smemf[10240];                       // 40 KB
    unsigned short* const smemh = (unsigned short*)smemf;
    unsigned short* const As0 = smemh;
    unsigned short* const As1 = smemh + 5120;
    unsigned short* const Bs0 = smemh + 10240;
    unsigned short* const Bs1 = smemh + 15360;

    const int tid = threadIdx.x;
    const int lane = tid & 63, wid = tid >> 6;
    const int wm = wid >> 1, wn = wid & 1;
    const int m0 = blockIdx.y * 128;
    const int n0 = blockIdx.x * 128;
    const int K = 256;

    f32x4 acc[4][4] = {};

    const int sr = tid & 127;
    const int spl = tid >> 7;
    const unsigned short* Ag = (spl ? Alo : Ahi) + (size_t)(m0 + sr) * K;
    const unsigned short* Bg = (spl ? Blo : Bhi) + (size_t)(n0 + sr) * K;
    unsigned short* Asw = (spl ? As1 : As0) + sr * 40;
    unsigned short* Bsw = (spl ? Bs1 : Bs0) + sr * 40;
    const int sw = sr & 3;

    const int kg = lane >> 4;
    const int fr = lane & 15;

    for (int k0 = 0; k0 < K; k0 += 32) {
        short8 av[4], bv[4];
#pragma unroll
        for (int c = 0; c < 4; ++c) {
            av[c] = LD8(Ag + k0 + c * 8);
            bv[c] = LD8(Bg + k0 + c * 8);
        }
        __syncthreads();
#pragma unroll
        for (int c = 0; c < 4; ++c) {
            *reinterpret_cast<short8*>(Asw + ((c ^ sw) * 8)) = av[c];
            *reinterpret_cast<short8*>(Bsw + ((c ^ sw) * 8)) = bv[c];
        }
        __syncthreads();

        short8 af[2][4], bf[2][4];
#pragma unroll
        for (int i = 0; i < 4; ++i) {
            const int ra = wm * 64 + i * 16 + fr;
            const int rb = wn * 64 + i * 16 + fr;
            af[0][i] = LD8(As0 + ra * 40 + ((kg ^ (ra & 3)) * 8));
            af[1][i] = LD8(As1 + ra * 40 + ((kg ^ (ra & 3)) * 8));
            bf[0][i] = LD8(Bs0 + rb * 40 + ((kg ^ (rb & 3)) * 8));
            bf[1][i] = LD8(Bs1 + rb * 40 + ((kg ^ (rb & 3)) * 8));
        }
#pragma unroll
        for (int i = 0; i < 4; ++i)
#pragma unroll
            for (int j = 0; j < 4; ++j) {
                acc[i][j] = __builtin_amdgcn_mfma_f32_16x16x32_bf16(
                    af[0][i], bf[0][j], acc[i][j], 0, 0, 0);
                acc[i][j] = __builtin_amdgcn_mfma_f32_16x16x32_bf16(
                    af[0][i], bf[1][j], acc[i][j], 0, 0, 0);
                acc[i][j] = __builtin_amdgcn_mfma_f32_16x16x32_bf16(
                    af[1][i], bf[0][j], acc[i][j], 0, 0, 0);
            }
    }
    __syncthreads();                                     // staging LDS dead

    // Epilogue: per-wave slab [16 n][65 m] -> PReLU+split -> Ef granules.
    float* slab = smemf + wid * 1040;
    const int t = (m0 >> 6) + wm;                        // this wave's t
    const int fq = lane >> 4;
    const float alpha = alphap[0];
#pragma unroll 1
    for (int j = 0; j < 4; ++j) {
#pragma unroll
        for (int i = 0; i < 4; ++i)
#pragma unroll
            for (int rr = 0; rr < 4; ++rr)
                slab[fr * 65 + i * 16 + fq * 4 + rr] = acc[i][j][rr];
        __syncthreads();
        const int b = lane;                              // m_local = batch
        const int nj = b >> 4;
#pragma unroll
        for (int ng = 0; ng < 4; ++ng) {
            const int n = n0 + wn * 64 + j * 16 + ng * 4;
            unsigned short hs[4], ls[4];
#pragma unroll
            for (int v = 0; v < 4; ++v) {
                float f = slab[(ng * 4 + v) * 65 + b] + benc[n + v];
                f = (f >= 0.f) ? f : alpha * f;
                hs[v] = f2bf(f);
                ls[v] = f2bf(f - bf2f(hs[v]));
            }
            uint2 hp, lp;
            hp.x = (unsigned)hs[0] | ((unsigned)hs[1] << 16);
            hp.y = (unsigned)hs[2] | ((unsigned)hs[3] << 16);
            lp.x = (unsigned)ls[0] | ((unsigned)ls[1] << 16);
            lp.y = (unsigned)ls[2] | ((unsigned)ls[3] << 16);
            const int s = n >> 5, kgn = (n >> 3) & 3, e0 = n & 7;
            const int ln = (b & 15) + 16 * kgn;
            const size_t base =
                ((((size_t)t * 32 + s) * 4 + nj) * 64 + ln) * 8 + e0;
            *reinterpret_cast<uint2*>(Ef + base) = hp;
            *reinterpret_cast<uint2*>(Ef + base + 32768) = lp;
        }
        __syncthreads();
    }
}

// ------------- weight prep: frag-order split planes ------------------------
__global__ __launch_bounds__(256) void wprep_k(
    const float* __restrict__ Wa, const float* __restrict__ Wb,
    unsigned short* __restrict__ Wf, int NS)
{
    __shared__ float tl[32][65];
    const int k0 = blockIdx.x * 32, j0 = blockIdx.y * 64;
    const int tid = threadIdx.x;
    {
        const int kk = tid >> 3, jq = tid & 7;
        const int k = k0 + kk;
        const float* src = (k < 1024) ? &Wa[(size_t)k * 4096]
                                      : &Wb[(size_t)(k - 1024) * 4096];
#pragma unroll
        for (int h = 0; h < 2; ++h) {
            const float4 v = *reinterpret_cast<const float4*>(
                &src[j0 + jq * 8 + h * 4]);
            tl[kk][jq * 8 + h * 4 + 0] = v.x; tl[kk][jq * 8 + h * 4 + 1] = v.y;
            tl[kk][jq * 8 + h * 4 + 2] = v.z; tl[kk][jq * 8 + h * 4 + 3] = v.w;
        }
    }
    __syncthreads();
    const int j = tid >> 2, kg = tid & 3;
    const int jg = j0 + j;
    const int g = jg >> 10, cc = jg & 1023;
    const int lb = cc >> 3, c = cc & 7;
    const int rloc = g * 8 + c;
    const int mi = rloc >> 4, r16 = rloc & 15;
    const int lane = r16 + 16 * kg;
    const int s = k0 >> 5;
    short8 hv, lv;
#pragma unroll
    for (int e = 0; e < 8; ++e) {
        const float x = tl[kg * 8 + e][j];
        const unsigned short h = f2bf(x);
        hv[e] = (short)h;
        lv[e] = (short)f2bf(x - bf2f(h));
    }
    const size_t oH = ((((size_t)lb * 2 + 0) * NS + s) * 2 + mi) * 512 + (size_t)lane * 8;
    const size_t oL = ((((size_t)lb * 2 + 1) * NS + s) * 2 + mi) * 512 + (size_t)lane * 8;
    *reinterpret_cast<short8*>(Wf + oH) = hv;
    *reinterpret_cast<short8*>(Wf + oL) = lv;
}

// ------------- h split init: hrow fp32 [64][1024] -> granule slot ----------
__global__ __launch_bounds__(256) void hsplit_k(
    const float* __restrict__ hrow, unsigned short* __restrict__ dst)
{
    const int idx = blockIdx.x * 256 + threadIdx.x;   // 8192 total
    const int b = idx >> 7, gc = idx & 127;
    const int k = gc * 8;
    short8 hv, lv;
#pragma unroll
    for (int e = 0; e < 8; ++e) {
        const float x = hrow[(size_t)b * 1024 + k + e];
        const unsigned short h = f2bf(x);
        hv[e] = (short)h;
        lv[e] = (short)f2bf(x - bf2f(h));
    }
    const int s = k >> 5, kg = (k >> 3) & 3, nj = b >> 4;
    const int l = (b & 15) + 16 * kg;
    const size_t oH = (((size_t)(0 * 32 + s) * 4 + nj) * 64 + l) * 8;
    const size_t oL = (((size_t)(1 * 32 + s) * 4 + nj) * 64 + l) * 8;
    *reinterpret_cast<short8*>(dst + oH) = hv;
    *reinterpret_cast<short8*>(dst + oL) = lv;
}

// ------------- permuted bias sum: out[lb*32+g*8+c] = bx[j]+bh[j] -----------
__global__ __launch_bounds__(256) void bsum_k(
    const float* __restrict__ bx, const float* __restrict__ bh,
    float* __restrict__ out)
{
    const int r = blockIdx.x * 256 + threadIdx.x;     // 4096
    const int lb = r >> 5, rl = r & 31;
    const int g = rl >> 3, c = rl & 7;
    const int j = g * 1024 + lb * 8 + c;
    out[r] = bx[j] + bh[j];
}

// ---------------- fused dual-layer LSTM, per-wave p2p flag sync ------------
// bar: per-block flags at bid*32 uints (256 x 128B).
__global__ __launch_bounds__(512, 2) void fused_lstm_k(
    const unsigned short* __restrict__ Ef,
    const unsigned short* __restrict__ Wf0,
    const unsigned short* __restrict__ Wf1,
    unsigned short* __restrict__ Y0, unsigned short* __restrict__ H1,
    const float* __restrict__ c0, const float* __restrict__ bsum0p,
    const float* __restrict__ bsum1p, float* __restrict__ hst1,
    unsigned* bar)
{
    __shared__ float Pred[8][32][66];
    __shared__ unsigned short hasmH[64][8];
    __shared__ unsigned short hasmL[64][8];

    const int tid = threadIdx.x;
    const int lane = tid & 63;                 // batch row for MFMA frags
    const int w = tid >> 6;                    // wave id 0..7
    const int bid = blockIdx.x;
    const int layer = bid >> 7;
    const int lb = bid & 127;

    const int NS = layer ? 64 : 48;            // K/32
    const int nEx = layer ? 4 : 2;             // cross subtiles per wave
    const int wNS = NS * 1024;                 // plane offset in weight shorts

    const unsigned short* Wf = layer ? Wf1 : Wf0;
    const unsigned short* wB =
        Wf + (size_t)lb * 2 * NS * 1024 + (size_t)lane * 8;

    // ---- load this wave's weight fragments into registers (once) ----
    short8 w00r[8], w01r[8], w10r[8], w11r[8];
#pragma unroll
    for (int i = 0; i < 8; ++i)
        if (i < 4 + nEx) {
            const int sg = (i < 4)
                ? (w * 4 + i)
                : (layer ? (32 + w * 4 + (i - 4)) : (32 + w * 2 + (i - 4)));
            const unsigned short* wp = wB + (size_t)sg * 1024;
            w00r[i] = LD8(wp);        w01r[i] = LD8(wp + 512);
            w10r[i] = LD8(wp + wNS);  w11r[i] = LD8(wp + wNS + 512);
        }

    // activation mapping: thread -> (b = lane, h-col = w)
    const int col = w;
    float c_ = c0[(size_t)layer * 65536 + (size_t)lane * 1024 + lb * 8 + col];
    const float* bsB = layer ? bsum1p : bsum0p;
    float bs[4];
#pragma unroll
    for (int g = 0; g < 4; ++g) bs[g] = bsB[lb * 32 + g * 8 + col];

#define MM(mi, nj, HH, HL)                                                     \
    acc[mi][nj] = __builtin_amdgcn_mfma_f32_16x16x32_bf16(                     \
        (mi) ? w01r[i] : w00r[i], HH, acc[mi][nj], 0, 0, 0);                   \
    acc[mi][nj] = __builtin_amdgcn_mfma_f32_16x16x32_bf16(                     \
        (mi) ? w01r[i] : w00r[i], HL, acc[mi][nj], 0, 0, 0);                   \
    acc[mi][nj] = __builtin_amdgcn_mfma_f32_16x16x32_bf16(                     \
        (mi) ? w11r[i] : w10r[i], HH, acc[mi][nj], 0, 0, 0);
#define SUBTILE(hp, po)                                                        \
    {                                                                          \
        const short8 h0v = LD8(hp),        h1v = LD8(hp + 512);                \
        const short8 h2v = LD8(hp + 1024), h3v = LD8(hp + 1536);               \
        const short8 l0v = LD8(hp + po),        l1v = LD8(hp + po + 512);      \
        const short8 l2v = LD8(hp + po + 1024), l3v = LD8(hp + po + 1536);     \
        MM(0, 0, h0v, l0v)  MM(0, 1, h1v, l1v)                                 \
        MM(0, 2, h2v, l2v)  MM(0, 3, h3v, l3v)                                 \
        MM(1, 0, h0v, l0v)  MM(1, 1, h1v, l1v)                                 \
        MM(1, 2, h2v, l2v)  MM(1, 3, h3v, l3v)                                 \
    }
    // wave-local poll of 16 producer flags (lanes 0..15), then compiler
    // barrier so the h loads below cannot be hoisted above the spin.
#define WPOLL(baseIdx, need)                                                   \
    {                                                                          \
        if (lane < 16) {                                                       \
            unsigned* p = bar + (size_t)((baseIdx) + lane) * 32;               \
            while (__hip_atomic_load(p, __ATOMIC_RELAXED,                      \
                                     __HIP_MEMORY_SCOPE_AGENT) < (need))       \
                __builtin_amdgcn_s_sleep(1);                                   \
        }                                                                      \
        __builtin_amdgcn_wave_barrier();                                       \
        asm volatile("" ::: "memory");                                         \
    }

    for (int r = 1; r <= 257; ++r) {
        const bool act = layer ? (r >= 2) : (r <= 256);
        if (act) {
            const int t = layer ? r - 2 : r - 1;
            const unsigned short* hOwn =
                (layer ? H1 : Y0) + (size_t)t * 131072 + (size_t)lane * 8;
            const unsigned short* hCross = layer
                ? Y0 + (size_t)(t + 1) * 131072 + (size_t)lane * 8
                : Ef + (size_t)t * 65536 + (size_t)lane * 8;
            const int poCross = layer ? 65536 : 32768;

            f32x4 acc[2][4] = {};

            // cross part: layer0 E (no dep); layer1 y0 slot t+1 (its 16
            // producers are L0 blocks w*16..w*16+15, flag >= r-1)
            if (layer) WPOLL(w * 16, (unsigned)(r - 1))
#pragma unroll
            for (int i = 4; i < 8; ++i)
                if (i < 4 + nEx) {
                    const int cs = layer ? (w * 4 + (i - 4)) : (w * 2 + (i - 4));
                    const unsigned short* hp = hCross + (size_t)cs * 2048;
                    SUBTILE(hp, poCross)
                }

            // own part: 16 own-layer producers (w*16..w*16+15), flag >= r-1
            if (r >= 2) WPOLL((layer ? 128 : 0) + w * 16, (unsigned)(r - 1))
#pragma unroll
            for (int i = 0; i < 4; ++i) {
                const unsigned short* hp = hOwn + (size_t)(w * 4 + i) * 2048;
                SUBTILE(hp, 65536)
            }

            // k-split partials: row = mi*16+(lane>>4)*4+rr, col = nj*16+(lane&15)
            {
                const int rq = (lane >> 4) * 4, cq = lane & 15;
#pragma unroll
                for (int mi = 0; mi < 2; ++mi)
#pragma unroll
                    for (int nj = 0; nj < 4; ++nj)
#pragma unroll
                        for (int rr = 0; rr < 4; ++rr)
                            Pred[w][mi * 16 + rq + rr][nj * 16 + cq] =
                                acc[mi][nj][rr];
            }
            __syncthreads();

            // activation: thread (b = lane, col = w)
            {
                float p[4];
#pragma unroll
                for (int g = 0; g < 4; ++g) {
                    const int row = g * 8 + col;
                    float s0 = 0.f;
#pragma unroll
                    for (int ww = 0; ww < 8; ++ww)
                        s0 += Pred[ww][row][lane];
                    p[g] = s0 + bs[g];
                }
                const float fg = sigmoidf_(p[0]);
                const float ig = sigmoidf_(p[1]);
                const float gg = tanhf(p[2]);
                const float og = sigmoidf_(p[3]);
                c_ = fmaf(fg, c_, ig * gg);
                const float h = og * tanhf(c_);
                const unsigned short hh = f2bf(h);
                hasmH[lane][col] = hh;
                hasmL[lane][col] = f2bf(h - bf2f(hh));
                if (layer && r == 257)
                    hst1[(size_t)(lb * 8 + col) * 64 + lane] = h;
            }
            __syncthreads();

            // granule store -> write-once slot t+1 (write-through atomics)
            if (tid < 128) {
                const int p = tid >> 6, b = tid & 63;
                unsigned short* hw =
                    (layer ? H1 : Y0) + (size_t)(t + 1) * 131072;
                const size_t off =
                    (((size_t)(p * 32 + (lb >> 2)) * 4 + (b >> 4)) * 64 +
                     ((b & 15) + 16 * (lb & 3))) * 8;
                const unsigned long long* src =
                    reinterpret_cast<const unsigned long long*>(
                        p ? &hasmL[b][0] : &hasmH[b][0]);
                unsigned long long* dst =
                    reinterpret_cast<unsigned long long*>(hw + off);
                __hip_atomic_store(dst, src[0], __ATOMIC_RELAXED,
                                   __HIP_MEMORY_SCOPE_AGENT);
                __hip_atomic_store(dst + 1, src[1], __ATOMIC_RELAXED,
                                   __HIP_MEMORY_SCOPE_AGENT);
            }
        }

        // ---- publish flag (stores drained by the barrier's vmcnt wait) ----
        if (r <= 256) {
            __syncthreads();
            if (tid == 0)
                __hip_atomic_store(bar + (size_t)bid * 32, (unsigned)r,
                                   __ATOMIC_RELAXED, __HIP_MEMORY_SCOPE_AGENT);
        }
    }
#undef WPOLL
#undef SUBTILE
#undef MM
}

// ---------------- classifier ------------------------------------------------
__global__ __launch_bounds__(256) void cls_k(
    const float* __restrict__ hfin, const float* __restrict__ Wc,
    const float* __restrict__ bcls, float* __restrict__ out)
{
    __shared__ float red[4][64];
    const int n = blockIdx.x;
    const int lane = threadIdx.x & 63, w = threadIdx.x >> 6;
    float acc = 0.f;
    for (int k = w * 256; k < w * 256 + 256; ++k)
        acc = fmaf(hfin[k * 64 + lane], Wc[k * 10 + n], acc);
    red[w][lane] = acc;
    __syncthreads();
    if (w == 0) {
        out[lane * 10 + n] = red[0][lane] + red[1][lane] + red[2][lane] +
                             red[3][lane] + bcls[n];
    }
}

extern "C" void kernel_launch(void* const* d_in, const int* in_sizes, int n_in,
                              void* d_out, int out_size, void* d_ws,
                              size_t ws_size, hipStream_t stream)
{
    const float* x    = (const float*)d_in[0];
    const float* h0   = (const float*)d_in[1];
    const float* c0   = (const float*)d_in[2];
    const float* Wenc = (const float*)d_in[3];
    const float* benc = (const float*)d_in[4];
    const float* alpha= (const float*)d_in[5];
    const float* Wx0  = (const float*)d_in[6];
    const float* bx0  = (const float*)d_in[7];
    const float* Wh0  = (const float*)d_in[8];
    const float* bh0  = (const float*)d_in[9];
    const float* Wx1  = (const float*)d_in[10];
    const float* bx1  = (const float*)d_in[11];
    const float* Wh1  = (const float*)d_in[12];
    const float* bh1  = (const float*)d_in[13];
    const float* Wcls = (const float*)d_in[14];
    const float* bcls = (const float*)d_in[15];
    float* out = (float*)d_out;

    // Workspace plan (floats): ~61.2M floats = 245 MB (budget >= 279 MB).
    float* ws = (float*)d_ws;
    size_t off = 0;
    unsigned short* Ef   = (unsigned short*)(ws + off); off += 8388608;   // 16.7M sh
    unsigned short* Wf0  = (unsigned short*)(ws + off); off += 6291456;   // 12.6M sh
    unsigned short* Wf1  = (unsigned short*)(ws + off); off += 8388608;   // 16.7M sh
    unsigned short* Y0   = (unsigned short*)(ws + off); off += 16842752;  // 257 slots
    unsigned short* H1   = (unsigned short*)(ws + off); off += 16842752;  // 257 slots
    unsigned short* Xhi  = (unsigned short*)(ws + off); off += 2097152;   // 4.2M sh
    unsigned short* Xlo  = (unsigned short*)(ws + off); off += 2097152;
    unsigned short* WeThi= (unsigned short*)(ws + off); off += 65536;     // 131K sh
    unsigned short* WeTlo= (unsigned short*)(ws + off); off += 65536;
    float* bsum0p = ws + off; off += 4096;
    float* bsum1p = ws + off; off += 4096;
    float* hst1   = ws + off; off += 65536;
    unsigned* bars = (unsigned*)(ws + off); off += 8192;   // 32 KB flag area

    (void)hipMemsetAsync(bars, 0, 32768, stream);

    // prologue (input-only deps)
    xsplit_k<<<2048, 256, 0, stream>>>(x, Xhi, Xlo);
    bsplitN_k<<<dim3(8, 8), 256, 0, stream>>>(Wenc, WeThi, WeTlo, 256, 512);
    enc_mfma_k<<<dim3(4, 128), 256, 0, stream>>>(
        Xhi, Xlo, WeThi, WeTlo, Ef, benc, alpha);
    wprep_k<<<dim3(48, 64), 256, 0, stream>>>(Wh0, Wx0, Wf0, 48);
    wprep_k<<<dim3(64, 64), 256, 0, stream>>>(Wh1, Wx1, Wf1, 64);
    hsplit_k<<<32, 256, 0, stream>>>(h0, Y0);                // h0_init -> slot 0
    hsplit_k<<<32, 256, 0, stream>>>(h0 + 65536, H1);        // h1_init -> slot 0
    bsum_k<<<16, 256, 0, stream>>>(bx0, bh0, bsum0p);
    bsum_k<<<16, 256, 0, stream>>>(bx1, bh1, bsum1p);

    // fused dual-layer LSTM, per-wave p2p flag sync (257 rounds)
    fused_lstm_k<<<256, 512, 0, stream>>>(Ef, Wf0, Wf1, Y0, H1, c0,
                                          bsum0p, bsum1p, hst1, bars);

    // classifier from layer-1 final h ([k][b])
    cls_k<<<dim3(10), 256, 0, stream>>>(hst1, Wcls, bcls, out);
}